// Round 13
// baseline (1997.665 us; speedup 1.0000x reference)
//
#include <hip/hip_runtime.h>
#include <hip/hip_bf16.h>

// GestureCNNLSTM: conv1(1->16,3x3,p1)+relu+pool2 -> conv2(16->32,3x3,p1)+relu+pool2
//  -> flatten 192 -> gx GEMM (+b_ih+b_hh) -> 512-step LSTM (H=256) -> 64-dim classifier.
// x [128][512][13][10] f32, out [128][64] f32. feat/gx f16 in ws (~159.8 MB).
//
// R12 LSTM: 256 threads/block (4 waves, 1/SIMD), thread t owns ALL 4 gate rows
// of hidden unit t (i=t, f=t+256, g=t+512, o=t+768) -> no gate exchange, one
// sync/step. Residency per row (128 f16 pairs): 39 LDS (160.7 KB) | 49 regs
// (196 VGPRs; 256-thr allocator granted 220 in R1 -> demand ~240 should fit) |
// 40 streamed (10 uint4 chunks, 160 KB/step, was 196). Grant signal: VGPR_Count.

typedef _Float16 half2v __attribute__((ext_vector_type(2)));
typedef _Float16 f16x8 __attribute__((ext_vector_type(8)));
typedef float f32x4 __attribute__((ext_vector_type(4)));

__device__ __forceinline__ float dot2f16(half2v a, half2v b, float c) {
#if defined(__has_builtin)
#if __has_builtin(__builtin_amdgcn_fdot2)
    return __builtin_amdgcn_fdot2(a, b, c, false);
#else
    return c + (float)a.x * (float)b.x + (float)a.y * (float)b.y;
#endif
#else
    return c + (float)a.x * (float)b.x + (float)a.y * (float)b.y;
#endif
}

__device__ __forceinline__ float dot2u(unsigned int a, unsigned int b, float c) {
    return dot2f16(__builtin_bit_cast(half2v, a), __builtin_bit_cast(half2v, b), c);
}

__device__ __forceinline__ unsigned int packf2(const float* p) {
    half2v hv;
    hv.x = (_Float16)p[0];
    hv.y = (_Float16)p[1];
    return __builtin_bit_cast(unsigned int, hv);
}

__device__ __forceinline__ unsigned int packff(float a, float b) {
    half2v hv;
    hv.x = (_Float16)a;
    hv.y = (_Float16)b;
    return __builtin_bit_cast(unsigned int, hv);
}

__device__ __forceinline__ half2v bch2(unsigned int u) {
    return __builtin_bit_cast(half2v, u);
}

__device__ __forceinline__ uint4 pack8(const float* p) {
    uint4 v;
    v.x = packf2(p + 0);
    v.y = packf2(p + 2);
    v.z = packf2(p + 4);
    v.w = packf2(p + 6);
    return v;
}

// ---------------- Kernel P1: pre-pack Wih (f32 -> f16), once ----------------
__global__ __launch_bounds__(256) void prepack_w_kernel(
    const float* __restrict__ Wih, uint4* __restrict__ wf)
{
    int idx = blockIdx.x * 256 + threadIdx.x;
    if (idx < 1024 * 192 / 8) wf[idx] = pack8(Wih + idx * 8);
}

// ---------------- Kernel P2: pre-pack W_hh stream section ----------------
// sw4[sc][r] (sc=0..9, r=0..1023) = pairs 88+4sc..88+4sc+3 (f32 elems 176+8sc..)
__global__ __launch_bounds__(256) void prepack_sw_kernel(
    const float* __restrict__ Whh, uint4* __restrict__ sw)
{
    int idx = blockIdx.x * 256 + threadIdx.x;
    if (idx < 10 * 1024) {
        int c = idx >> 10, r = idx & 1023;
        sw[idx] = pack8(Whh + (size_t)r * 256 + 176 + 8 * c);
    }
}

// ---------------- Kernel A: fused conv1+pool1+conv2+pool2 ----------------
__global__ __launch_bounds__(256) void conv_kernel(
    const float* __restrict__ x,     // [65536][13][10]
    const float* __restrict__ c1w,   // [16][1][3][3]
    const float* __restrict__ c1b,   // [16]
    const float* __restrict__ c2w,   // [32][16][3][3]
    const float* __restrict__ c2b,   // [32]
    _Float16* __restrict__ feat)     // [65536][192]
{
    __shared__ float w1t[9 * 16];
    __shared__ float b1s[16];
    __shared__ unsigned int w2h[8 * 9 * 32];   // [icp][k][oc]
    __shared__ float b2s[32];
    __shared__ float xp[4][14 * 12];
    __shared__ __align__(4) _Float16 p1ph[4][8 * 7 * 16];  // [y*7+x][oc]

    const int tid = threadIdx.x;

    for (int idx = tid; idx < 144; idx += 256) {
        int oc = idx / 9, k = idx % 9;
        w1t[k * 16 + oc] = c1w[idx];
    }
    if (tid < 16) b1s[tid] = c1b[tid];
    for (int idx = tid; idx < 2304; idx += 256) {
        int icp = idx / 288, rem = idx % 288;
        int k = rem / 32, oc = rem % 32;
        float a = c2w[oc * 144 + (2 * icp) * 9 + k];
        float b = c2w[oc * 144 + (2 * icp + 1) * 9 + k];
        w2h[idx] = packff(a, b);
    }
    if (tid < 32) b2s[tid] = c2b[tid];

    const int w = tid >> 6;
    const int lane = tid & 63;
    const int img = blockIdx.x * 4 + w;

    for (int i = lane; i < 14 * 12; i += 64) xp[w][i] = 0.f;
    for (int i = lane; i < 8 * 7 * 16; i += 64) p1ph[w][i] = (_Float16)0.f;
    __syncthreads();

    const float* xin = x + (size_t)img * 130;
    for (int i = lane; i < 130; i += 64) {
        int r = i / 10, c = i % 10;
        xp[w][(r + 1) * 12 + (c + 1)] = xin[i];
    }
    __syncthreads();

    {
        const int oc = lane & 15, q = lane >> 4;
        #pragma unroll
        for (int i = 0; i < 8; i++) {
            int pos = i * 4 + q;
            if (pos < 30) {
                int ph = pos / 5, pw = pos % 5;
                float cmax = -1e30f;
                #pragma unroll
                for (int pt = 0; pt < 4; pt++) {
                    int Y = 2 * ph + (pt >> 1), X = 2 * pw + (pt & 1);
                    float s = 0.f;
                    #pragma unroll
                    for (int k = 0; k < 9; k++) {
                        int dy = k / 3, dx = k % 3;
                        s += w1t[k * 16 + oc] * xp[w][(Y + dy) * 12 + X + dx];
                    }
                    cmax = fmaxf(cmax, s);
                }
                p1ph[w][((ph + 1) * 7 + (pw + 1)) * 16 + oc] =
                    (_Float16)fmaxf(0.f, cmax + b1s[oc]);
            }
        }
    }
    __syncthreads();

    {
        const int oc = lane & 31, pw2 = lane >> 5;
        float acc[3][4] = {};
        const _Float16* P = &p1ph[w][0];

        #pragma unroll
        for (int icp = 0; icp < 8; icp++) {
            unsigned int hreg[32];
            #pragma unroll
            for (int y = 0; y < 8; y++)
                #pragma unroll
                for (int xx = 0; xx < 4; xx++) {
                    int xcol = 2 * pw2 + xx;
                    hreg[y * 4 + xx] =
                        *(const unsigned int*)&P[(y * 7 + xcol) * 16 + 2 * icp];
                }
            #pragma unroll
            for (int k = 0; k < 9; k++) {
                int dy = k / 3, dx = k % 3;
                unsigned int wv = w2h[(icp * 9 + k) * 32 + oc];
                #pragma unroll
                for (int ph2 = 0; ph2 < 3; ph2++) {
                    #pragma unroll
                    for (int pt = 0; pt < 4; pt++) {
                        int y = 2 * ph2 + (pt >> 1) + dy;
                        int xx2 = (pt & 1) + dx;
                        acc[ph2][pt] = dot2u(wv, hreg[y * 4 + xx2], acc[ph2][pt]);
                    }
                }
            }
        }
        float bias = b2s[oc];
        _Float16* fo = feat + (size_t)img * 192;
        #pragma unroll
        for (int ph2 = 0; ph2 < 3; ph2++) {
            float m = fmaxf(fmaxf(acc[ph2][0], acc[ph2][1]),
                            fmaxf(acc[ph2][2], acc[ph2][3]));
            fo[oc * 6 + ph2 * 2 + pw2] = (_Float16)fmaxf(0.f, m + bias);
        }
    }
}

// ---------------- Kernel B: gx = feat @ W_ih^T + bias via MFMA f16 ----------
__global__ __launch_bounds__(256) void gemm_gx_kernel(
    const _Float16* __restrict__ feat,  // [65536][192]
    const _Float16* __restrict__ wf16,  // [1024][192] (prepacked)
    const float* __restrict__ bih,
    const float* __restrict__ bhh,
    _Float16* __restrict__ gx)          // [65536][1024]
{
    __shared__ uint4 As4[128][13];
    __shared__ uint4 Ws4[128][13];

    const int tid = threadIdx.x;
    const int n0 = blockIdx.x * 128;
    const int m0 = blockIdx.y * 128;

    const int w = tid >> 6;
    const int lane = tid & 63;
    const int lm = lane & 15;
    const int lk = lane >> 4;

    f32x4 acc[2][8] = {};

    #pragma unroll
    for (int half = 0; half < 2; half++) {
        if (half) __syncthreads();
        const int kbase = half * 12;
        #pragma unroll
        for (int it = 0; it < 6; it++) {
            int q = tid + it * 256;
            int r = q / 12, c = q % 12;
            As4[r][c] = *(const uint4*)(feat + (size_t)(m0 + r) * 192 + (kbase + c) * 8);
            Ws4[r][c] = *(const uint4*)(wf16 + (size_t)(n0 + r) * 192 + (kbase + c) * 8);
        }
        __syncthreads();

        #pragma unroll
        for (int ks = 0; ks < 3; ks++) {
            f16x8 wf[2], af[8];
            #pragma unroll
            for (int nf = 0; nf < 2; nf++)
                wf[nf] = __builtin_bit_cast(f16x8, Ws4[w * 32 + nf * 16 + lm][ks * 4 + lk]);
            #pragma unroll
            for (int mf = 0; mf < 8; mf++)
                af[mf] = __builtin_bit_cast(f16x8, As4[mf * 16 + lm][ks * 4 + lk]);
            #pragma unroll
            for (int nf = 0; nf < 2; nf++)
                #pragma unroll
                for (int mf = 0; mf < 8; mf++)
                    acc[nf][mf] = __builtin_amdgcn_mfma_f32_16x16x32_f16(
                        wf[nf], af[mf], acc[nf][mf], 0, 0, 0);
        }
    }

    #pragma unroll
    for (int nf = 0; nf < 2; nf++) {
        int nb = n0 + w * 32 + nf * 16 + lk * 4;
        float4 b1 = *(const float4*)&bih[nb];
        float4 b2 = *(const float4*)&bhh[nb];
        float bs0 = b1.x + b2.x, bs1 = b1.y + b2.y;
        float bs2 = b1.z + b2.z, bs3 = b1.w + b2.w;
        #pragma unroll
        for (int mf = 0; mf < 8; mf++) {
            int m = m0 + mf * 16 + lm;
            union { _Float16 h[4]; uint2 u; } pk;
            pk.h[0] = (_Float16)(acc[nf][mf][0] + bs0);
            pk.h[1] = (_Float16)(acc[nf][mf][1] + bs1);
            pk.h[2] = (_Float16)(acc[nf][mf][2] + bs2);
            pk.h[3] = (_Float16)(acc[nf][mf][3] + bs3);
            *(uint2*)&gx[(size_t)m * 1024 + nb] = pk.u;
        }
    }
}

// ---------------- Kernel C: 512-step LSTM + classifier (256 thr, 4 rows/thr) --
// Thread t owns gate rows {t, t+256, t+512, t+768} = (i,f,g,o) of hidden unit t.
// Per row (128 pairs): 0..35 wl4 | 36..37 wl2 | 38 wl1 | 39..87 regs (49) |
// 88..127 streamed (10 uint4). One __syncthreads per step (double-buffered h).
__global__ __launch_bounds__(256, 1) void lstm_kernel(
    const _Float16* __restrict__ gx, // [128][512][1024]
    const float* __restrict__ Whh,   // [1024][256]
    const uint4* __restrict__ sw,    // [10][1024]
    const float* __restrict__ clsw,  // [64][256]
    const float* __restrict__ clsb,  // [64]
    float* __restrict__ out)         // [128][64]
{
    __shared__ uint4 wl4[9][1024];                     // 147.5 KB: pairs 0..35
    __shared__ uint2 wl2[1024];                        // 8 KB: pairs 36..37
    __shared__ unsigned int wl1[1024];                 // 4 KB: pair 38
    __shared__ __align__(16) _Float16 hbuf[2][256];    // 1 KB

    const int t = threadIdx.x;
    const int b = blockIdx.x;

    // register weights: pairs 39..87 (f32 elems 78..175), 4 rows x 49
    half2v wr[4][49];
    #pragma unroll
    for (int g = 0; g < 4; g++) {
        const int row = t + 256 * g;
        const float* wp = Whh + (size_t)row * 256;
        #pragma unroll
        for (int ch = 0; ch < 9; ch++) wl4[ch][row] = pack8(wp + 8 * ch);
        uint2 v2;
        v2.x = packf2(wp + 72);
        v2.y = packf2(wp + 74);
        wl2[row] = v2;
        wl1[row] = packf2(wp + 76);
        #pragma unroll
        for (int q = 0; q < 49; q++) wr[g][q] = bch2(packf2(wp + 78 + 2 * q));
    }
    hbuf[0][t] = (_Float16)0.f;
    __syncthreads();

    float c = 0.f;
    int cur = 0;
    const _Float16* gxb = gx + (size_t)b * 512 * 1024;
    float ga0 = (float)gxb[t];
    float ga1 = (float)gxb[t + 256];
    float ga2 = (float)gxb[t + 512];
    float ga3 = (float)gxb[t + 768];

    for (int step = 0; step < 512; step++) {
        const _Float16* gxn = gxb + (size_t)((step + 1) & 511) * 1024;
        _Float16 n0 = gxn[t];
        _Float16 n1 = gxn[t + 256];
        _Float16 n2 = gxn[t + 512];
        _Float16 n3 = gxn[t + 768];

        float a0 = ga0, a1 = ga1, a2 = ga2, a3 = ga3;
        const uint4* hb4 = (const uint4*)&hbuf[cur][0];  // 32 uint4 chunks

        // STREAM: h chunks 22..31 <-> sw chunks 0..9 (issue early)
        #pragma unroll
        for (int sc = 0; sc < 10; sc++) {
            uint4 u0 = sw[sc * 1024 + t];
            uint4 u1 = sw[sc * 1024 + t + 256];
            uint4 u2 = sw[sc * 1024 + t + 512];
            uint4 u3 = sw[sc * 1024 + t + 768];
            uint4 hv = hb4[22 + sc];
            a0 = dot2u(u0.x, hv.x, a0); a0 = dot2u(u0.y, hv.y, a0);
            a0 = dot2u(u0.z, hv.z, a0); a0 = dot2u(u0.w, hv.w, a0);
            a1 = dot2u(u1.x, hv.x, a1); a1 = dot2u(u1.y, hv.y, a1);
            a1 = dot2u(u1.z, hv.z, a1); a1 = dot2u(u1.w, hv.w, a1);
            a2 = dot2u(u2.x, hv.x, a2); a2 = dot2u(u2.y, hv.y, a2);
            a2 = dot2u(u2.z, hv.z, a2); a2 = dot2u(u2.w, hv.w, a2);
            a3 = dot2u(u3.x, hv.x, a3); a3 = dot2u(u3.y, hv.y, a3);
            a3 = dot2u(u3.z, hv.z, a3); a3 = dot2u(u3.w, hv.w, a3);
        }
        // LDS wl4: h chunks 0..8
        #pragma unroll
        for (int ch = 0; ch < 9; ch++) {
            uint4 u0 = wl4[ch][t];
            uint4 u1 = wl4[ch][t + 256];
            uint4 u2 = wl4[ch][t + 512];
            uint4 u3 = wl4[ch][t + 768];
            uint4 hv = hb4[ch];
            a0 = dot2u(u0.x, hv.x, a0); a0 = dot2u(u0.y, hv.y, a0);
            a0 = dot2u(u0.z, hv.z, a0); a0 = dot2u(u0.w, hv.w, a0);
            a1 = dot2u(u1.x, hv.x, a1); a1 = dot2u(u1.y, hv.y, a1);
            a1 = dot2u(u1.z, hv.z, a1); a1 = dot2u(u1.w, hv.w, a1);
            a2 = dot2u(u2.x, hv.x, a2); a2 = dot2u(u2.y, hv.y, a2);
            a2 = dot2u(u2.z, hv.z, a2); a2 = dot2u(u2.w, hv.w, a2);
            a3 = dot2u(u3.x, hv.x, a3); a3 = dot2u(u3.y, hv.y, a3);
            a3 = dot2u(u3.z, hv.z, a3); a3 = dot2u(u3.w, hv.w, a3);
        }
        // chunk 9: wl2 (.x.y), wl1 (.z), wr[.][0] (.w)
        {
            uint4 hv = hb4[9];
            uint2 u20 = wl2[t];
            uint2 u21 = wl2[t + 256];
            uint2 u22 = wl2[t + 512];
            uint2 u23 = wl2[t + 768];
            a0 = dot2u(u20.x, hv.x, a0); a0 = dot2u(u20.y, hv.y, a0);
            a1 = dot2u(u21.x, hv.x, a1); a1 = dot2u(u21.y, hv.y, a1);
            a2 = dot2u(u22.x, hv.x, a2); a2 = dot2u(u22.y, hv.y, a2);
            a3 = dot2u(u23.x, hv.x, a3); a3 = dot2u(u23.y, hv.y, a3);
            a0 = dot2u(wl1[t], hv.z, a0);
            a1 = dot2u(wl1[t + 256], hv.z, a1);
            a2 = dot2u(wl1[t + 512], hv.z, a2);
            a3 = dot2u(wl1[t + 768], hv.z, a3);
            a0 = dot2f16(wr[0][0], bch2(hv.w), a0);
            a1 = dot2f16(wr[1][0], bch2(hv.w), a1);
            a2 = dot2f16(wr[2][0], bch2(hv.w), a2);
            a3 = dot2f16(wr[3][0], bch2(hv.w), a3);
        }
        // REG: h chunks 10..21, wr[.][1+4j+k]
        #pragma unroll
        for (int j = 0; j < 12; j++) {
            uint4 hv = hb4[10 + j];
            a0 = dot2f16(wr[0][1 + 4 * j], bch2(hv.x), a0);
            a0 = dot2f16(wr[0][2 + 4 * j], bch2(hv.y), a0);
            a0 = dot2f16(wr[0][3 + 4 * j], bch2(hv.z), a0);
            a0 = dot2f16(wr[0][4 + 4 * j], bch2(hv.w), a0);
            a1 = dot2f16(wr[1][1 + 4 * j], bch2(hv.x), a1);
            a1 = dot2f16(wr[1][2 + 4 * j], bch2(hv.y), a1);
            a1 = dot2f16(wr[1][3 + 4 * j], bch2(hv.z), a1);
            a1 = dot2f16(wr[1][4 + 4 * j], bch2(hv.w), a1);
            a2 = dot2f16(wr[2][1 + 4 * j], bch2(hv.x), a2);
            a2 = dot2f16(wr[2][2 + 4 * j], bch2(hv.y), a2);
            a2 = dot2f16(wr[2][3 + 4 * j], bch2(hv.z), a2);
            a2 = dot2f16(wr[2][4 + 4 * j], bch2(hv.w), a2);
            a3 = dot2f16(wr[3][1 + 4 * j], bch2(hv.x), a3);
            a3 = dot2f16(wr[3][2 + 4 * j], bch2(hv.y), a3);
            a3 = dot2f16(wr[3][3 + 4 * j], bch2(hv.z), a3);
            a3 = dot2f16(wr[3][4 + 4 * j], bch2(hv.w), a3);
        }

        // gates: a0=i, a1=f, a2=g, a3=o for hidden unit t
        float i_ = 1.f / (1.f + __expf(-a0));
        float f_ = 1.f / (1.f + __expf(-a1));
        float g_ = 1.f - 2.f / (__expf(2.f * a2) + 1.f);
        float o_ = 1.f / (1.f + __expf(-a3));
        c = f_ * c + i_ * g_;
        float th = 1.f - 2.f / (__expf(2.f * c) + 1.f);
        hbuf[cur ^ 1][t] = (_Float16)(o_ * th);
        __syncthreads();
        cur ^= 1;
        ga0 = (float)n0; ga1 = (float)n1; ga2 = (float)n2; ga3 = (float)n3;
    }

    if (t < 64) {
        const float* cw = clsw + t * 256;
        float s = clsb[t];
        for (int k = 0; k < 256; k++) s += cw[k] * (float)hbuf[cur][k];
        out[b * 64 + t] = s;
    }
}

extern "C" void kernel_launch(void* const* d_in, const int* in_sizes, int n_in,
                              void* d_out, int out_size, void* d_ws, size_t ws_size,
                              hipStream_t stream) {
    const float* x    = (const float*)d_in[0];
    const float* c1w  = (const float*)d_in[1];
    const float* c1b  = (const float*)d_in[2];
    const float* c2w  = (const float*)d_in[3];
    const float* c2b  = (const float*)d_in[4];
    const float* Wih  = (const float*)d_in[5];
    const float* bih  = (const float*)d_in[6];
    const float* Whh  = (const float*)d_in[7];
    const float* bhh  = (const float*)d_in[8];
    const float* clsw = (const float*)d_in[9];
    const float* clsb = (const float*)d_in[10];

    _Float16* feat = (_Float16*)d_ws;                     // 25.2 MB
    _Float16* gx   = feat + (size_t)65536 * 192;          // 134.2 MB
    uint4* aux     = (uint4*)(gx + (size_t)65536 * 1024); // 384 KB union:
    // aux = wf16 for gemm, then overwritten as sw (10240 uint4) for lstm.
    float* outp = (float*)d_out;

    hipLaunchKernelGGL(prepack_w_kernel, dim3(96), dim3(256), 0, stream, Wih, aux);
    hipLaunchKernelGGL(conv_kernel, dim3(16384), dim3(256), 0, stream,
                       x, c1w, c1b, c2w, c2b, feat);
    hipLaunchKernelGGL(gemm_gx_kernel, dim3(8, 512), dim3(256), 0, stream,
                       feat, (const _Float16*)aux, bih, bhh, gx);
    hipLaunchKernelGGL(prepack_sw_kernel, dim3(40), dim3(256), 0, stream, Whh, aux);
    hipLaunchKernelGGL(lstm_kernel, dim3(128), dim3(256), 0, stream,
                       gx, Whh, aux, clsw, clsb, outp);
}

// Round 14
// 1124.504 us; speedup vs baseline: 1.7765x; 1.7765x over previous
//
#include <hip/hip_runtime.h>
#include <hip/hip_bf16.h>

// GestureCNNLSTM: conv1(1->16,3x3,p1)+relu+pool2 -> conv2(16->32,3x3,p1)+relu+pool2
//  -> flatten 192 -> gx GEMM (+b_ih+b_hh) -> 512-step LSTM (H=256) -> 64-dim classifier.
// x [128][512][13][10] f32, out [128][64] f32. feat/gx f16 in ws (~159.8 MB).
//
// R13: LSTM = R9/R11 proven structure (858us; at ~83% of per-CU L2->L1 fill
// ceiling for its 188 KB/step weight stream — residency exploration exhausted:
// 512t/128VGPR spill-free streaming beats AGPR (R6/R7), 1024t (R4), 256t (R12),
// cross-CU split (R10)). Conv phase-2: icp-paired uint2 im2col reads (halves
// LDS read count). GEMM: K-split 2-blocks/CU (R11).

typedef _Float16 half2v __attribute__((ext_vector_type(2)));
typedef _Float16 f16x8 __attribute__((ext_vector_type(8)));
typedef float f32x4 __attribute__((ext_vector_type(4)));

__device__ __forceinline__ float dot2f16(half2v a, half2v b, float c) {
#if defined(__has_builtin)
#if __has_builtin(__builtin_amdgcn_fdot2)
    return __builtin_amdgcn_fdot2(a, b, c, false);
#else
    return c + (float)a.x * (float)b.x + (float)a.y * (float)b.y;
#endif
#else
    return c + (float)a.x * (float)b.x + (float)a.y * (float)b.y;
#endif
}

__device__ __forceinline__ float dot2u(unsigned int a, unsigned int b, float c) {
    return dot2f16(__builtin_bit_cast(half2v, a), __builtin_bit_cast(half2v, b), c);
}

__device__ __forceinline__ unsigned int packf2(const float* p) {
    half2v hv;
    hv.x = (_Float16)p[0];
    hv.y = (_Float16)p[1];
    return __builtin_bit_cast(unsigned int, hv);
}

__device__ __forceinline__ unsigned int packff(float a, float b) {
    half2v hv;
    hv.x = (_Float16)a;
    hv.y = (_Float16)b;
    return __builtin_bit_cast(unsigned int, hv);
}

__device__ __forceinline__ half2v bch2(unsigned int u) {
    return __builtin_bit_cast(half2v, u);
}

__device__ __forceinline__ uint4 pack8(const float* p) {
    uint4 v;
    v.x = packf2(p + 0);
    v.y = packf2(p + 2);
    v.z = packf2(p + 4);
    v.w = packf2(p + 6);
    return v;
}

// ---------------- Kernel P1: pre-pack Wih (f32 -> f16), once ----------------
__global__ __launch_bounds__(256) void prepack_w_kernel(
    const float* __restrict__ Wih, uint4* __restrict__ wf)
{
    int idx = blockIdx.x * 256 + threadIdx.x;
    if (idx < 1024 * 192 / 8) wf[idx] = pack8(Wih + idx * 8);
}

// ---------------- Kernel P2: pre-pack W_hh stream section ----------------
// sw[c][r] (c=0..11, r=0..1023) = pairs 80+4c..80+4c+3 of row r (f32 elems 160+8c..)
__global__ __launch_bounds__(256) void prepack_sw_kernel(
    const float* __restrict__ Whh, uint4* __restrict__ sw)
{
    int idx = blockIdx.x * 256 + threadIdx.x;
    if (idx < 12 * 1024) {
        int c = idx >> 10, r = idx & 1023;
        sw[idx] = pack8(Whh + (size_t)r * 256 + 160 + 8 * c);
    }
}

// ---------------- Kernel A: fused conv1+pool1+conv2+pool2 ----------------
__global__ __launch_bounds__(256) void conv_kernel(
    const float* __restrict__ x,     // [65536][13][10]
    const float* __restrict__ c1w,   // [16][1][3][3]
    const float* __restrict__ c1b,   // [16]
    const float* __restrict__ c2w,   // [32][16][3][3]
    const float* __restrict__ c2b,   // [32]
    _Float16* __restrict__ feat)     // [65536][192]
{
    __shared__ float w1t[9 * 16];
    __shared__ float b1s[16];
    __shared__ unsigned int w2h[8 * 9 * 32];   // [icp][k][oc]
    __shared__ float b2s[32];
    __shared__ float xp[4][14 * 12];
    __shared__ __align__(8) _Float16 p1ph[4][8 * 7 * 16];  // [y*7+x][oc]

    const int tid = threadIdx.x;

    for (int idx = tid; idx < 144; idx += 256) {
        int oc = idx / 9, k = idx % 9;
        w1t[k * 16 + oc] = c1w[idx];
    }
    if (tid < 16) b1s[tid] = c1b[tid];
    for (int idx = tid; idx < 2304; idx += 256) {
        int icp = idx / 288, rem = idx % 288;
        int k = rem / 32, oc = rem % 32;
        float a = c2w[oc * 144 + (2 * icp) * 9 + k];
        float b = c2w[oc * 144 + (2 * icp + 1) * 9 + k];
        w2h[idx] = packff(a, b);
    }
    if (tid < 32) b2s[tid] = c2b[tid];

    const int w = tid >> 6;
    const int lane = tid & 63;
    const int img = blockIdx.x * 4 + w;

    for (int i = lane; i < 14 * 12; i += 64) xp[w][i] = 0.f;
    for (int i = lane; i < 8 * 7 * 16; i += 64) p1ph[w][i] = (_Float16)0.f;
    __syncthreads();

    const float* xin = x + (size_t)img * 130;
    for (int i = lane; i < 130; i += 64) {
        int r = i / 10, c = i % 10;
        xp[w][(r + 1) * 12 + (c + 1)] = xin[i];
    }
    __syncthreads();

    {
        const int oc = lane & 15, q = lane >> 4;
        #pragma unroll
        for (int i = 0; i < 8; i++) {
            int pos = i * 4 + q;
            if (pos < 30) {
                int ph = pos / 5, pw = pos % 5;
                float cmax = -1e30f;
                #pragma unroll
                for (int pt = 0; pt < 4; pt++) {
                    int Y = 2 * ph + (pt >> 1), X = 2 * pw + (pt & 1);
                    float s = 0.f;
                    #pragma unroll
                    for (int k = 0; k < 9; k++) {
                        int dy = k / 3, dx = k % 3;
                        s += w1t[k * 16 + oc] * xp[w][(Y + dy) * 12 + X + dx];
                    }
                    cmax = fmaxf(cmax, s);
                }
                p1ph[w][((ph + 1) * 7 + (pw + 1)) * 16 + oc] =
                    (_Float16)fmaxf(0.f, cmax + b1s[oc]);
            }
        }
    }
    __syncthreads();

    // phase 2: conv2+relu+pool via dot2; icp processed in PAIRS via uint2
    // im2col reads (offset 32*pos + 4*icp is 8B-aligned for even icp).
    {
        const int oc = lane & 31, pw2 = lane >> 5;
        float acc[3][4] = {};
        const _Float16* P = &p1ph[w][0];

        #pragma unroll
        for (int icp2 = 0; icp2 < 4; icp2++) {
            uint2 hreg[32];   // .x = icp 2*icp2, .y = icp 2*icp2+1
            #pragma unroll
            for (int y = 0; y < 8; y++)
                #pragma unroll
                for (int xx = 0; xx < 4; xx++) {
                    int xcol = 2 * pw2 + xx;
                    hreg[y * 4 + xx] =
                        *(const uint2*)&P[(y * 7 + xcol) * 16 + 4 * icp2];
                }
            #pragma unroll
            for (int k = 0; k < 9; k++) {
                int dy = k / 3, dx = k % 3;
                unsigned int wv0 = w2h[((2 * icp2 + 0) * 9 + k) * 32 + oc];
                unsigned int wv1 = w2h[((2 * icp2 + 1) * 9 + k) * 32 + oc];
                #pragma unroll
                for (int ph2 = 0; ph2 < 3; ph2++) {
                    #pragma unroll
                    for (int pt = 0; pt < 4; pt++) {
                        int y = 2 * ph2 + (pt >> 1) + dy;
                        int xx2 = (pt & 1) + dx;
                        uint2 hv = hreg[y * 4 + xx2];
                        acc[ph2][pt] = dot2u(wv0, hv.x, acc[ph2][pt]);
                        acc[ph2][pt] = dot2u(wv1, hv.y, acc[ph2][pt]);
                    }
                }
            }
        }
        float bias = b2s[oc];
        _Float16* fo = feat + (size_t)img * 192;
        #pragma unroll
        for (int ph2 = 0; ph2 < 3; ph2++) {
            float m = fmaxf(fmaxf(acc[ph2][0], acc[ph2][1]),
                            fmaxf(acc[ph2][2], acc[ph2][3]));
            fo[oc * 6 + ph2 * 2 + pw2] = (_Float16)fmaxf(0.f, m + bias);
        }
    }
}

// ---------------- Kernel B: gx = feat @ W_ih^T + bias via MFMA f16 ----------
__global__ __launch_bounds__(256) void gemm_gx_kernel(
    const _Float16* __restrict__ feat,  // [65536][192]
    const _Float16* __restrict__ wf16,  // [1024][192] (prepacked)
    const float* __restrict__ bih,
    const float* __restrict__ bhh,
    _Float16* __restrict__ gx)          // [65536][1024]
{
    __shared__ uint4 As4[128][13];
    __shared__ uint4 Ws4[128][13];

    const int tid = threadIdx.x;
    const int n0 = blockIdx.x * 128;
    const int m0 = blockIdx.y * 128;

    const int w = tid >> 6;
    const int lane = tid & 63;
    const int lm = lane & 15;
    const int lk = lane >> 4;

    f32x4 acc[2][8] = {};

    #pragma unroll
    for (int half = 0; half < 2; half++) {
        if (half) __syncthreads();
        const int kbase = half * 12;
        #pragma unroll
        for (int it = 0; it < 6; it++) {
            int q = tid + it * 256;
            int r = q / 12, c = q % 12;
            As4[r][c] = *(const uint4*)(feat + (size_t)(m0 + r) * 192 + (kbase + c) * 8);
            Ws4[r][c] = *(const uint4*)(wf16 + (size_t)(n0 + r) * 192 + (kbase + c) * 8);
        }
        __syncthreads();

        #pragma unroll
        for (int ks = 0; ks < 3; ks++) {
            f16x8 wf[2], af[8];
            #pragma unroll
            for (int nf = 0; nf < 2; nf++)
                wf[nf] = __builtin_bit_cast(f16x8, Ws4[w * 32 + nf * 16 + lm][ks * 4 + lk]);
            #pragma unroll
            for (int mf = 0; mf < 8; mf++)
                af[mf] = __builtin_bit_cast(f16x8, As4[mf * 16 + lm][ks * 4 + lk]);
            #pragma unroll
            for (int nf = 0; nf < 2; nf++)
                #pragma unroll
                for (int mf = 0; mf < 8; mf++)
                    acc[nf][mf] = __builtin_amdgcn_mfma_f32_16x16x32_f16(
                        wf[nf], af[mf], acc[nf][mf], 0, 0, 0);
        }
    }

    #pragma unroll
    for (int nf = 0; nf < 2; nf++) {
        int nb = n0 + w * 32 + nf * 16 + lk * 4;
        float4 b1 = *(const float4*)&bih[nb];
        float4 b2 = *(const float4*)&bhh[nb];
        float bs0 = b1.x + b2.x, bs1 = b1.y + b2.y;
        float bs2 = b1.z + b2.z, bs3 = b1.w + b2.w;
        #pragma unroll
        for (int mf = 0; mf < 8; mf++) {
            int m = m0 + mf * 16 + lm;
            union { _Float16 h[4]; uint2 u; } pk;
            pk.h[0] = (_Float16)(acc[nf][mf][0] + bs0);
            pk.h[1] = (_Float16)(acc[nf][mf][1] + bs1);
            pk.h[2] = (_Float16)(acc[nf][mf][2] + bs2);
            pk.h[3] = (_Float16)(acc[nf][mf][3] + bs3);
            *(uint2*)&gx[(size_t)m * 1024 + nb] = pk.u;
        }
    }
}

// ---------------- Kernel C: 512-step LSTM + classifier (R9/R11, proven) ------
// 128 blocks x 512 threads (8 waves, 2/SIMD). Thread t owns rows r0=t, r1=t+512.
// Per row (128 f16 pairs): 0..35 wl4 LDS | 36..37 wl2 LDS | 38..79 regs (42) |
// 80..127 streamed from sw (12 uint4 chunks, L2-hot, zero-reuse cold fetch).
__global__ __launch_bounds__(512, 2) void lstm_kernel(
    const _Float16* __restrict__ gx, // [128][512][1024]
    const float* __restrict__ Whh,   // [1024][256]
    const uint4* __restrict__ sw,    // [12][1024]
    const float* __restrict__ clsw,  // [64][256]
    const float* __restrict__ clsb,  // [64]
    float* __restrict__ out)         // [128][64]
{
    __shared__ uint4 wl4[9][1024];                     // 144 KB: pairs 0..35
    __shared__ uint2 wl2[1024];                        // 8 KB: pairs 36..37
    __shared__ __align__(16) _Float16 hbuf[2][256];    // 1 KB
    __shared__ float xg[512];                          // 2 KB

    const int t = threadIdx.x;
    const int b = blockIdx.x;
    const int r0 = t, r1 = t + 512;

    const float* w0 = Whh + (size_t)r0 * 256;
    const float* w1 = Whh + (size_t)r1 * 256;

    #pragma unroll
    for (int ch = 0; ch < 9; ch++) {
        wl4[ch][r0] = pack8(w0 + 8 * ch);
        wl4[ch][r1] = pack8(w1 + 8 * ch);
    }
    {
        uint2 v0, v1;
        v0.x = packf2(w0 + 72); v0.y = packf2(w0 + 74);
        v1.x = packf2(w1 + 72); v1.y = packf2(w1 + 74);
        wl2[r0] = v0;
        wl2[r1] = v1;
    }
    half2v wr0[42], wr1[42];
    #pragma unroll
    for (int q = 0; q < 42; q++) {
        wr0[q] = bch2(packf2(w0 + 76 + 2 * q));
        wr1[q] = bch2(packf2(w1 + 76 + 2 * q));
    }
    if (t < 256) hbuf[0][t] = (_Float16)0.f;
    __syncthreads();

    float c = 0.f;
    int cur = 0;
    const _Float16* gxb = gx + (size_t)b * 512 * 1024;
    float ga = (float)gxb[r0];
    float gb = (float)gxb[r1];

    for (int step = 0; step < 512; step++) {
        const _Float16* gxn = gxb + (size_t)((step + 1) & 511) * 1024;
        _Float16 na = gxn[r0];
        _Float16 nb = gxn[r1];

        float acc0 = ga, acc1 = gb;
        const uint4* hb4 = (const uint4*)&hbuf[cur][0];  // 32 chunks of 4 pairs

        // STREAM section: h chunks 20..31 <-> sw chunks 0..11
        #pragma unroll
        for (int sc = 0; sc < 12; sc++) {
            uint4 u0 = sw[sc * 1024 + r0];
            uint4 u1 = sw[sc * 1024 + r1];
            uint4 hv = hb4[20 + sc];
            acc0 = dot2f16(bch2(u0.x), bch2(hv.x), acc0);
            acc0 = dot2f16(bch2(u0.y), bch2(hv.y), acc0);
            acc0 = dot2f16(bch2(u0.z), bch2(hv.z), acc0);
            acc0 = dot2f16(bch2(u0.w), bch2(hv.w), acc0);
            acc1 = dot2f16(bch2(u1.x), bch2(hv.x), acc1);
            acc1 = dot2f16(bch2(u1.y), bch2(hv.y), acc1);
            acc1 = dot2f16(bch2(u1.z), bch2(hv.z), acc1);
            acc1 = dot2f16(bch2(u1.w), bch2(hv.w), acc1);
        }
        // LDS wl4: h chunks 0..8
        #pragma unroll
        for (int ch = 0; ch < 9; ch++) {
            uint4 u0 = wl4[ch][r0];
            uint4 u1 = wl4[ch][r1];
            uint4 hv = hb4[ch];
            acc0 = dot2f16(bch2(u0.x), bch2(hv.x), acc0);
            acc0 = dot2f16(bch2(u0.y), bch2(hv.y), acc0);
            acc0 = dot2f16(bch2(u0.z), bch2(hv.z), acc0);
            acc0 = dot2f16(bch2(u0.w), bch2(hv.w), acc0);
            acc1 = dot2f16(bch2(u1.x), bch2(hv.x), acc1);
            acc1 = dot2f16(bch2(u1.y), bch2(hv.y), acc1);
            acc1 = dot2f16(bch2(u1.z), bch2(hv.z), acc1);
            acc1 = dot2f16(bch2(u1.w), bch2(hv.w), acc1);
        }
        // LDS wl2 (pairs 36,37) + regs (pairs 38,39) use h chunk 9
        {
            uint4 hv = hb4[9];
            uint2 u0 = wl2[r0];
            uint2 u1 = wl2[r1];
            acc0 = dot2f16(bch2(u0.x), bch2(hv.x), acc0);
            acc0 = dot2f16(bch2(u0.y), bch2(hv.y), acc0);
            acc1 = dot2f16(bch2(u1.x), bch2(hv.x), acc1);
            acc1 = dot2f16(bch2(u1.y), bch2(hv.y), acc1);
            acc0 = dot2f16(wr0[0], bch2(hv.z), acc0);
            acc0 = dot2f16(wr0[1], bch2(hv.w), acc0);
            acc1 = dot2f16(wr1[0], bch2(hv.z), acc1);
            acc1 = dot2f16(wr1[1], bch2(hv.w), acc1);
        }
        // REG section: h chunks 10..19, wr 2..41
        #pragma unroll
        for (int cc = 0; cc < 10; cc++) {
            uint4 hv = hb4[10 + cc];
            acc0 = dot2f16(wr0[2 + 4 * cc + 0], bch2(hv.x), acc0);
            acc0 = dot2f16(wr0[2 + 4 * cc + 1], bch2(hv.y), acc0);
            acc0 = dot2f16(wr0[2 + 4 * cc + 2], bch2(hv.z), acc0);
            acc0 = dot2f16(wr0[2 + 4 * cc + 3], bch2(hv.w), acc0);
            acc1 = dot2f16(wr1[2 + 4 * cc + 0], bch2(hv.x), acc1);
            acc1 = dot2f16(wr1[2 + 4 * cc + 1], bch2(hv.y), acc1);
            acc1 = dot2f16(wr1[2 + 4 * cc + 2], bch2(hv.z), acc1);
            acc1 = dot2f16(wr1[2 + 4 * cc + 3], bch2(hv.w), acc1);
        }

        if (t >= 256) {           // acc0 = f_j, acc1 = o_j for j = t-256
            xg[t - 256] = acc0;
            xg[t] = acc1;
        }
        __syncthreads();
        if (t < 256) {            // acc0 = i_j, acc1 = g_j for j = t
            float i_ = 1.f / (1.f + __expf(-acc0));
            float g_ = 1.f - 2.f / (__expf(2.f * acc1) + 1.f);
            float f_ = 1.f / (1.f + __expf(-xg[t]));
            float o_ = 1.f / (1.f + __expf(-xg[t + 256]));
            c = f_ * c + i_ * g_;
            float th = 1.f - 2.f / (__expf(2.f * c) + 1.f);
            float h = o_ * th;
            hbuf[cur ^ 1][t] = (_Float16)h;
        }
        __syncthreads();
        cur ^= 1;
        ga = (float)na;
        gb = (float)nb;
    }

    if (t < 64) {
        const float* cw = clsw + t * 256;
        float s = clsb[t];
        for (int k = 0; k < 256; k++) s += cw[k] * (float)hbuf[cur][k];
        out[b * 64 + t] = s;
    }
}

extern "C" void kernel_launch(void* const* d_in, const int* in_sizes, int n_in,
                              void* d_out, int out_size, void* d_ws, size_t ws_size,
                              hipStream_t stream) {
    const float* x    = (const float*)d_in[0];
    const float* c1w  = (const float*)d_in[1];
    const float* c1b  = (const float*)d_in[2];
    const float* c2w  = (const float*)d_in[3];
    const float* c2b  = (const float*)d_in[4];
    const float* Wih  = (const float*)d_in[5];
    const float* bih  = (const float*)d_in[6];
    const float* Whh  = (const float*)d_in[7];
    const float* bhh  = (const float*)d_in[8];
    const float* clsw = (const float*)d_in[9];
    const float* clsb = (const float*)d_in[10];

    _Float16* feat = (_Float16*)d_ws;                     // 25.2 MB
    _Float16* gx   = feat + (size_t)65536 * 192;          // 134.2 MB
    uint4* aux     = (uint4*)(gx + (size_t)65536 * 1024); // 384 KB union:
    // aux = wf16 for gemm, then overwritten as sw for lstm (sequential stream).
    float* outp = (float*)d_out;

    hipLaunchKernelGGL(prepack_w_kernel, dim3(96), dim3(256), 0, stream, Wih, aux);
    hipLaunchKernelGGL(conv_kernel, dim3(16384), dim3(256), 0, stream,
                       x, c1w, c1b, c2w, c2b, feat);
    hipLaunchKernelGGL(gemm_gx_kernel, dim3(8, 512), dim3(256), 0, stream,
                       feat, (const _Float16*)aux, bih, bhh, gx);
    hipLaunchKernelGGL(prepack_sw_kernel, dim3(48), dim3(256), 0, stream, Whh, aux);
    hipLaunchKernelGGL(lstm_kernel, dim3(128), dim3(512), 0, stream,
                       gx, Whh, aux, clsw, clsb, outp);
}

// Round 15
// 1106.371 us; speedup vs baseline: 1.8056x; 1.0164x over previous
//
#include <hip/hip_runtime.h>
#include <hip/hip_bf16.h>

// GestureCNNLSTM: conv1(1->16,3x3,p1)+relu+pool2 -> conv2(16->32,3x3,p1)+relu+pool2
//  -> flatten 192 -> gx GEMM (+b_ih+b_hh) -> 512-step LSTM (H=256) -> 64-dim classifier.
// x [128][512][13][10] f32, out [128][64] f32. feat/gx f16 in ws (~159.8 MB).
//
// R14 = exact revert to R11's best-measured configuration (1104.8 us):
//  - conv: R9/R11 phase-2 (scalar-uint im2col; R13's uint2 pairing cost +20us)
//  - gemm: K-split MFMA, 2 blocks/CU
//  - lstm: R9/R11 512-thr structure, 857us = stream-fill floor (196 KB/step
//    zero-reuse weight stream; all residency alternatives measured & refuted).

typedef _Float16 half2v __attribute__((ext_vector_type(2)));
typedef _Float16 f16x8 __attribute__((ext_vector_type(8)));
typedef float f32x4 __attribute__((ext_vector_type(4)));

__device__ __forceinline__ float dot2f16(half2v a, half2v b, float c) {
#if defined(__has_builtin)
#if __has_builtin(__builtin_amdgcn_fdot2)
    return __builtin_amdgcn_fdot2(a, b, c, false);
#else
    return c + (float)a.x * (float)b.x + (float)a.y * (float)b.y;
#endif
#else
    return c + (float)a.x * (float)b.x + (float)a.y * (float)b.y;
#endif
}

__device__ __forceinline__ float dot2u(unsigned int a, unsigned int b, float c) {
    return dot2f16(__builtin_bit_cast(half2v, a), __builtin_bit_cast(half2v, b), c);
}

__device__ __forceinline__ unsigned int packf2(const float* p) {
    half2v hv;
    hv.x = (_Float16)p[0];
    hv.y = (_Float16)p[1];
    return __builtin_bit_cast(unsigned int, hv);
}

__device__ __forceinline__ unsigned int packff(float a, float b) {
    half2v hv;
    hv.x = (_Float16)a;
    hv.y = (_Float16)b;
    return __builtin_bit_cast(unsigned int, hv);
}

__device__ __forceinline__ half2v bch2(unsigned int u) {
    return __builtin_bit_cast(half2v, u);
}

__device__ __forceinline__ uint4 pack8(const float* p) {
    uint4 v;
    v.x = packf2(p + 0);
    v.y = packf2(p + 2);
    v.z = packf2(p + 4);
    v.w = packf2(p + 6);
    return v;
}

// ---------------- Kernel P1: pre-pack Wih (f32 -> f16), once ----------------
__global__ __launch_bounds__(256) void prepack_w_kernel(
    const float* __restrict__ Wih, uint4* __restrict__ wf)
{
    int idx = blockIdx.x * 256 + threadIdx.x;
    if (idx < 1024 * 192 / 8) wf[idx] = pack8(Wih + idx * 8);
}

// ---------------- Kernel P2: pre-pack W_hh stream section ----------------
// sw[c][r] (c=0..11, r=0..1023) = pairs 80+4c..80+4c+3 of row r (f32 elems 160+8c..)
__global__ __launch_bounds__(256) void prepack_sw_kernel(
    const float* __restrict__ Whh, uint4* __restrict__ sw)
{
    int idx = blockIdx.x * 256 + threadIdx.x;
    if (idx < 12 * 1024) {
        int c = idx >> 10, r = idx & 1023;
        sw[idx] = pack8(Whh + (size_t)r * 256 + 160 + 8 * c);
    }
}

// ---------------- Kernel A: fused conv1+pool1+conv2+pool2 ----------------
__global__ __launch_bounds__(256) void conv_kernel(
    const float* __restrict__ x,     // [65536][13][10]
    const float* __restrict__ c1w,   // [16][1][3][3]
    const float* __restrict__ c1b,   // [16]
    const float* __restrict__ c2w,   // [32][16][3][3]
    const float* __restrict__ c2b,   // [32]
    _Float16* __restrict__ feat)     // [65536][192]
{
    __shared__ float w1t[9 * 16];
    __shared__ float b1s[16];
    __shared__ unsigned int w2h[8 * 9 * 32];   // [icp][k][oc]
    __shared__ float b2s[32];
    __shared__ float xp[4][14 * 12];
    __shared__ __align__(4) _Float16 p1ph[4][8 * 7 * 16];  // [y*7+x][oc]

    const int tid = threadIdx.x;

    for (int idx = tid; idx < 144; idx += 256) {
        int oc = idx / 9, k = idx % 9;
        w1t[k * 16 + oc] = c1w[idx];
    }
    if (tid < 16) b1s[tid] = c1b[tid];
    for (int idx = tid; idx < 2304; idx += 256) {
        int icp = idx / 288, rem = idx % 288;
        int k = rem / 32, oc = rem % 32;
        float a = c2w[oc * 144 + (2 * icp) * 9 + k];
        float b = c2w[oc * 144 + (2 * icp + 1) * 9 + k];
        w2h[idx] = packff(a, b);
    }
    if (tid < 32) b2s[tid] = c2b[tid];

    const int w = tid >> 6;
    const int lane = tid & 63;
    const int img = blockIdx.x * 4 + w;

    for (int i = lane; i < 14 * 12; i += 64) xp[w][i] = 0.f;
    for (int i = lane; i < 8 * 7 * 16; i += 64) p1ph[w][i] = (_Float16)0.f;
    __syncthreads();

    const float* xin = x + (size_t)img * 130;
    for (int i = lane; i < 130; i += 64) {
        int r = i / 10, c = i % 10;
        xp[w][(r + 1) * 12 + (c + 1)] = xin[i];
    }
    __syncthreads();

    {
        const int oc = lane & 15, q = lane >> 4;
        #pragma unroll
        for (int i = 0; i < 8; i++) {
            int pos = i * 4 + q;
            if (pos < 30) {
                int ph = pos / 5, pw = pos % 5;
                float cmax = -1e30f;
                #pragma unroll
                for (int pt = 0; pt < 4; pt++) {
                    int Y = 2 * ph + (pt >> 1), X = 2 * pw + (pt & 1);
                    float s = 0.f;
                    #pragma unroll
                    for (int k = 0; k < 9; k++) {
                        int dy = k / 3, dx = k % 3;
                        s += w1t[k * 16 + oc] * xp[w][(Y + dy) * 12 + X + dx];
                    }
                    cmax = fmaxf(cmax, s);
                }
                p1ph[w][((ph + 1) * 7 + (pw + 1)) * 16 + oc] =
                    (_Float16)fmaxf(0.f, cmax + b1s[oc]);
            }
        }
    }
    __syncthreads();

    // phase 2: conv2+relu+pool via dot2, register im2col (scalar uint reads)
    {
        const int oc = lane & 31, pw2 = lane >> 5;
        float acc[3][4] = {};
        const _Float16* P = &p1ph[w][0];

        #pragma unroll
        for (int icp = 0; icp < 8; icp++) {
            unsigned int hreg[32];
            #pragma unroll
            for (int y = 0; y < 8; y++)
                #pragma unroll
                for (int xx = 0; xx < 4; xx++) {
                    int xcol = 2 * pw2 + xx;
                    hreg[y * 4 + xx] =
                        *(const unsigned int*)&P[(y * 7 + xcol) * 16 + 2 * icp];
                }
            #pragma unroll
            for (int k = 0; k < 9; k++) {
                int dy = k / 3, dx = k % 3;
                unsigned int wv = w2h[(icp * 9 + k) * 32 + oc];
                #pragma unroll
                for (int ph2 = 0; ph2 < 3; ph2++) {
                    #pragma unroll
                    for (int pt = 0; pt < 4; pt++) {
                        int y = 2 * ph2 + (pt >> 1) + dy;
                        int xx2 = (pt & 1) + dx;
                        acc[ph2][pt] = dot2u(wv, hreg[y * 4 + xx2], acc[ph2][pt]);
                    }
                }
            }
        }
        float bias = b2s[oc];
        _Float16* fo = feat + (size_t)img * 192;
        #pragma unroll
        for (int ph2 = 0; ph2 < 3; ph2++) {
            float m = fmaxf(fmaxf(acc[ph2][0], acc[ph2][1]),
                            fmaxf(acc[ph2][2], acc[ph2][3]));
            fo[oc * 6 + ph2 * 2 + pw2] = (_Float16)fmaxf(0.f, m + bias);
        }
    }
}

// ---------------- Kernel B: gx = feat @ W_ih^T + bias via MFMA f16 ----------
__global__ __launch_bounds__(256) void gemm_gx_kernel(
    const _Float16* __restrict__ feat,  // [65536][192]
    const _Float16* __restrict__ wf16,  // [1024][192] (prepacked)
    const float* __restrict__ bih,
    const float* __restrict__ bhh,
    _Float16* __restrict__ gx)          // [65536][1024]
{
    __shared__ uint4 As4[128][13];
    __shared__ uint4 Ws4[128][13];

    const int tid = threadIdx.x;
    const int n0 = blockIdx.x * 128;
    const int m0 = blockIdx.y * 128;

    const int w = tid >> 6;
    const int lane = tid & 63;
    const int lm = lane & 15;
    const int lk = lane >> 4;

    f32x4 acc[2][8] = {};

    #pragma unroll
    for (int half = 0; half < 2; half++) {
        if (half) __syncthreads();
        const int kbase = half * 12;
        #pragma unroll
        for (int it = 0; it < 6; it++) {
            int q = tid + it * 256;
            int r = q / 12, c = q % 12;
            As4[r][c] = *(const uint4*)(feat + (size_t)(m0 + r) * 192 + (kbase + c) * 8);
            Ws4[r][c] = *(const uint4*)(wf16 + (size_t)(n0 + r) * 192 + (kbase + c) * 8);
        }
        __syncthreads();

        #pragma unroll
        for (int ks = 0; ks < 3; ks++) {
            f16x8 wf[2], af[8];
            #pragma unroll
            for (int nf = 0; nf < 2; nf++)
                wf[nf] = __builtin_bit_cast(f16x8, Ws4[w * 32 + nf * 16 + lm][ks * 4 + lk]);
            #pragma unroll
            for (int mf = 0; mf < 8; mf++)
                af[mf] = __builtin_bit_cast(f16x8, As4[mf * 16 + lm][ks * 4 + lk]);
            #pragma unroll
            for (int nf = 0; nf < 2; nf++)
                #pragma unroll
                for (int mf = 0; mf < 8; mf++)
                    acc[nf][mf] = __builtin_amdgcn_mfma_f32_16x16x32_f16(
                        wf[nf], af[mf], acc[nf][mf], 0, 0, 0);
        }
    }

    #pragma unroll
    for (int nf = 0; nf < 2; nf++) {
        int nb = n0 + w * 32 + nf * 16 + lk * 4;
        float4 b1 = *(const float4*)&bih[nb];
        float4 b2 = *(const float4*)&bhh[nb];
        float bs0 = b1.x + b2.x, bs1 = b1.y + b2.y;
        float bs2 = b1.z + b2.z, bs3 = b1.w + b2.w;
        #pragma unroll
        for (int mf = 0; mf < 8; mf++) {
            int m = m0 + mf * 16 + lm;
            union { _Float16 h[4]; uint2 u; } pk;
            pk.h[0] = (_Float16)(acc[nf][mf][0] + bs0);
            pk.h[1] = (_Float16)(acc[nf][mf][1] + bs1);
            pk.h[2] = (_Float16)(acc[nf][mf][2] + bs2);
            pk.h[3] = (_Float16)(acc[nf][mf][3] + bs3);
            *(uint2*)&gx[(size_t)m * 1024 + nb] = pk.u;
        }
    }
}

// ---------------- Kernel C: 512-step LSTM + classifier (R9/R11, proven) ------
// 128 blocks x 512 threads (8 waves, 2/SIMD). Thread t owns rows r0=t, r1=t+512.
// Per row (128 f16 pairs): 0..35 wl4 LDS | 36..37 wl2 LDS | 38..79 regs (42) |
// 80..127 streamed from sw (12 uint4 chunks, L2-hot, zero-reuse cold fetch).
__global__ __launch_bounds__(512, 2) void lstm_kernel(
    const _Float16* __restrict__ gx, // [128][512][1024]
    const float* __restrict__ Whh,   // [1024][256]
    const uint4* __restrict__ sw,    // [12][1024]
    const float* __restrict__ clsw,  // [64][256]
    const float* __restrict__ clsb,  // [64]
    float* __restrict__ out)         // [128][64]
{
    __shared__ uint4 wl4[9][1024];                     // 144 KB: pairs 0..35
    __shared__ uint2 wl2[1024];                        // 8 KB: pairs 36..37
    __shared__ __align__(16) _Float16 hbuf[2][256];    // 1 KB
    __shared__ float xg[512];                          // 2 KB

    const int t = threadIdx.x;
    const int b = blockIdx.x;
    const int r0 = t, r1 = t + 512;

    const float* w0 = Whh + (size_t)r0 * 256;
    const float* w1 = Whh + (size_t)r1 * 256;

    #pragma unroll
    for (int ch = 0; ch < 9; ch++) {
        wl4[ch][r0] = pack8(w0 + 8 * ch);
        wl4[ch][r1] = pack8(w1 + 8 * ch);
    }
    {
        uint2 v0, v1;
        v0.x = packf2(w0 + 72); v0.y = packf2(w0 + 74);
        v1.x = packf2(w1 + 72); v1.y = packf2(w1 + 74);
        wl2[r0] = v0;
        wl2[r1] = v1;
    }
    half2v wr0[42], wr1[42];
    #pragma unroll
    for (int q = 0; q < 42; q++) {
        wr0[q] = bch2(packf2(w0 + 76 + 2 * q));
        wr1[q] = bch2(packf2(w1 + 76 + 2 * q));
    }
    if (t < 256) hbuf[0][t] = (_Float16)0.f;
    __syncthreads();

    float c = 0.f;
    int cur = 0;
    const _Float16* gxb = gx + (size_t)b * 512 * 1024;
    float ga = (float)gxb[r0];
    float gb = (float)gxb[r1];

    for (int step = 0; step < 512; step++) {
        const _Float16* gxn = gxb + (size_t)((step + 1) & 511) * 1024;
        _Float16 na = gxn[r0];
        _Float16 nb = gxn[r1];

        float acc0 = ga, acc1 = gb;
        const uint4* hb4 = (const uint4*)&hbuf[cur][0];  // 32 chunks of 4 pairs

        // STREAM section: h chunks 20..31 <-> sw chunks 0..11
        #pragma unroll
        for (int sc = 0; sc < 12; sc++) {
            uint4 u0 = sw[sc * 1024 + r0];
            uint4 u1 = sw[sc * 1024 + r1];
            uint4 hv = hb4[20 + sc];
            acc0 = dot2f16(bch2(u0.x), bch2(hv.x), acc0);
            acc0 = dot2f16(bch2(u0.y), bch2(hv.y), acc0);
            acc0 = dot2f16(bch2(u0.z), bch2(hv.z), acc0);
            acc0 = dot2f16(bch2(u0.w), bch2(hv.w), acc0);
            acc1 = dot2f16(bch2(u1.x), bch2(hv.x), acc1);
            acc1 = dot2f16(bch2(u1.y), bch2(hv.y), acc1);
            acc1 = dot2f16(bch2(u1.z), bch2(hv.z), acc1);
            acc1 = dot2f16(bch2(u1.w), bch2(hv.w), acc1);
        }
        // LDS wl4: h chunks 0..8
        #pragma unroll
        for (int ch = 0; ch < 9; ch++) {
            uint4 u0 = wl4[ch][r0];
            uint4 u1 = wl4[ch][r1];
            uint4 hv = hb4[ch];
            acc0 = dot2f16(bch2(u0.x), bch2(hv.x), acc0);
            acc0 = dot2f16(bch2(u0.y), bch2(hv.y), acc0);
            acc0 = dot2f16(bch2(u0.z), bch2(hv.z), acc0);
            acc0 = dot2f16(bch2(u0.w), bch2(hv.w), acc0);
            acc1 = dot2f16(bch2(u1.x), bch2(hv.x), acc1);
            acc1 = dot2f16(bch2(u1.y), bch2(hv.y), acc1);
            acc1 = dot2f16(bch2(u1.z), bch2(hv.z), acc1);
            acc1 = dot2f16(bch2(u1.w), bch2(hv.w), acc1);
        }
        // LDS wl2 (pairs 36,37) + regs (pairs 38,39) use h chunk 9
        {
            uint4 hv = hb4[9];
            uint2 u0 = wl2[r0];
            uint2 u1 = wl2[r1];
            acc0 = dot2f16(bch2(u0.x), bch2(hv.x), acc0);
            acc0 = dot2f16(bch2(u0.y), bch2(hv.y), acc0);
            acc1 = dot2f16(bch2(u1.x), bch2(hv.x), acc1);
            acc1 = dot2f16(bch2(u1.y), bch2(hv.y), acc1);
            acc0 = dot2f16(wr0[0], bch2(hv.z), acc0);
            acc0 = dot2f16(wr0[1], bch2(hv.w), acc0);
            acc1 = dot2f16(wr1[0], bch2(hv.z), acc1);
            acc1 = dot2f16(wr1[1], bch2(hv.w), acc1);
        }
        // REG section: h chunks 10..19, wr 2..41
        #pragma unroll
        for (int cc = 0; cc < 10; cc++) {
            uint4 hv = hb4[10 + cc];
            acc0 = dot2f16(wr0[2 + 4 * cc + 0], bch2(hv.x), acc0);
            acc0 = dot2f16(wr0[2 + 4 * cc + 1], bch2(hv.y), acc0);
            acc0 = dot2f16(wr0[2 + 4 * cc + 2], bch2(hv.z), acc0);
            acc0 = dot2f16(wr0[2 + 4 * cc + 3], bch2(hv.w), acc0);
            acc1 = dot2f16(wr1[2 + 4 * cc + 0], bch2(hv.x), acc1);
            acc1 = dot2f16(wr1[2 + 4 * cc + 1], bch2(hv.y), acc1);
            acc1 = dot2f16(wr1[2 + 4 * cc + 2], bch2(hv.z), acc1);
            acc1 = dot2f16(wr1[2 + 4 * cc + 3], bch2(hv.w), acc1);
        }

        if (t >= 256) {           // acc0 = f_j, acc1 = o_j for j = t-256
            xg[t - 256] = acc0;
            xg[t] = acc1;
        }
        __syncthreads();
        if (t < 256) {            // acc0 = i_j, acc1 = g_j for j = t
            float i_ = 1.f / (1.f + __expf(-acc0));
            float g_ = 1.f - 2.f / (__expf(2.f * acc1) + 1.f);
            float f_ = 1.f / (1.f + __expf(-xg[t]));
            float o_ = 1.f / (1.f + __expf(-xg[t + 256]));
            c = f_ * c + i_ * g_;
            float th = 1.f - 2.f / (__expf(2.f * c) + 1.f);
            float h = o_ * th;
            hbuf[cur ^ 1][t] = (_Float16)h;
        }
        __syncthreads();
        cur ^= 1;
        ga = (float)na;
        gb = (float)nb;
    }

    if (t < 64) {
        const float* cw = clsw + t * 256;
        float s = clsb[t];
        for (int k = 0; k < 256; k++) s += cw[k] * (float)hbuf[cur][k];
        out[b * 64 + t] = s;
    }
}

extern "C" void kernel_launch(void* const* d_in, const int* in_sizes, int n_in,
                              void* d_out, int out_size, void* d_ws, size_t ws_size,
                              hipStream_t stream) {
    const float* x    = (const float*)d_in[0];
    const float* c1w  = (const float*)d_in[1];
    const float* c1b  = (const float*)d_in[2];
    const float* c2w  = (const float*)d_in[3];
    const float* c2b  = (const float*)d_in[4];
    const float* Wih  = (const float*)d_in[5];
    const float* bih  = (const float*)d_in[6];
    const float* Whh  = (const float*)d_in[7];
    const float* bhh  = (const float*)d_in[8];
    const float* clsw = (const float*)d_in[9];
    const float* clsb = (const float*)d_in[10];

    _Float16* feat = (_Float16*)d_ws;                     // 25.2 MB
    _Float16* gx   = feat + (size_t)65536 * 192;          // 134.2 MB
    uint4* aux     = (uint4*)(gx + (size_t)65536 * 1024); // 384 KB union:
    // aux = wf16 for gemm, then overwritten as sw for lstm (sequential stream).
    float* outp = (float*)d_out;

    hipLaunchKernelGGL(prepack_w_kernel, dim3(96), dim3(256), 0, stream, Wih, aux);
    hipLaunchKernelGGL(conv_kernel, dim3(16384), dim3(256), 0, stream,
                       x, c1w, c1b, c2w, c2b, feat);
    hipLaunchKernelGGL(gemm_gx_kernel, dim3(8, 512), dim3(256), 0, stream,
                       feat, (const _Float16*)aux, bih, bhh, gx);
    hipLaunchKernelGGL(prepack_sw_kernel, dim3(48), dim3(256), 0, stream, Whh, aux);
    hipLaunchKernelGGL(lstm_kernel, dim3(128), dim3(512), 0, stream,
                       gx, Whh, aux, clsw, clsb, outp);
}